// Round 1
// baseline (395.192 us; speedup 1.0000x reference)
//
#include <hip/hip_runtime.h>
#include <math.h>

// Problem constants
#define EMBED   2048
#define NHEADS  16
#define HD      128
#define S_TOT   4096
#define BATCH   64

typedef __attribute__((ext_vector_type(8))) short short8v;
typedef __attribute__((ext_vector_type(4))) short short4v;
typedef __attribute__((ext_vector_type(2))) short short2v;
typedef __attribute__((ext_vector_type(4))) float floatx4;

// fp32 -> bf16, round-to-nearest-even
__device__ __forceinline__ unsigned short f2bf(float f) {
    unsigned u = __builtin_bit_cast(unsigned, f);
    u += 0x7fffu + ((u >> 16) & 1u);
    return (unsigned short)(u >> 16);
}

// DPP row-rotate (within 16-lane rows) move; CTRL = 0x120 + N for row_ror:N
template <int CTRL>
__device__ __forceinline__ float dppf(float x) {
    int r = __builtin_amdgcn_mov_dpp(__builtin_bit_cast(int, x), CTRL, 0xF, 0xF, false);
    return __builtin_bit_cast(float, r);
}
__device__ __forceinline__ float rowmax16(float v) {
    v = fmaxf(v, dppf<0x121>(v));
    v = fmaxf(v, dppf<0x122>(v));
    v = fmaxf(v, dppf<0x124>(v));
    v = fmaxf(v, dppf<0x128>(v));
    return v;
}
__device__ __forceinline__ float rowsum16(float v) {
    v += dppf<0x121>(v);
    v += dppf<0x122>(v);
    v += dppf<0x124>(v);
    v += dppf<0x128>(v);
    return v;
}

// ---------------------------------------------------------------------------
// K1: fused QKV projection. out = x @ [Wq|Wk|Wv] + bias, M=64, N=2304, K=2048
// grid (72 n-tiles of 32 cols, 8 k-splits of 256), block 256.
// Atomic accumulate into zero-initialized buffers; chunk 0 folds bias.
// ---------------------------------------------------------------------------
__launch_bounds__(256)
__global__ void k1_qkv(const float* __restrict__ x,
                       const float* __restrict__ Wq, const float* __restrict__ bq,
                       const float* __restrict__ Wk, const float* __restrict__ bk,
                       const float* __restrict__ Wv, const float* __restrict__ bv,
                       float* __restrict__ qbuf, float* __restrict__ knew,
                       float* __restrict__ vnew) {
    const int tx = threadIdx.x & 31;
    const int ty = threadIdx.x >> 5;   // 0..7
    const int nt = blockIdx.x;         // 0..71
    const int kc = blockIdx.y;         // 0..7
    const int k0 = kc * 256;
    const int col0 = nt * 32;

    const float* W; const float* bias; float* out; int ldW;
    int cbase;
    if (col0 < 2048)       { W = Wq; bias = bq; out = qbuf; ldW = 2048; cbase = col0; }
    else if (col0 < 2176)  { W = Wk; bias = bk; out = knew; ldW = 128;  cbase = col0 - 2048; }
    else                   { W = Wv; bias = bv; out = vnew; ldW = 128;  cbase = col0 - 2176; }
    const int col = cbase + tx;

    __shared__ __align__(16) float xs[64][68];   // 64 rows x 64 k, pad to 68

    float acc[8] = {0, 0, 0, 0, 0, 0, 0, 0};

    for (int sub = 0; sub < 4; ++sub) {
        const int kb = k0 + sub * 64;
        // stage x[0..64][kb..kb+64], fully coalesced
        #pragma unroll
        for (int i = 0; i < 4; ++i) {
            int c = threadIdx.x + i * 256;   // float4 chunk id 0..1023
            int r = c >> 4;
            int cc = (c & 15) << 2;
            float4 v = *(const float4*)(x + (size_t)r * EMBED + kb + cc);
            *(float4*)&xs[r][cc] = v;
        }
        __syncthreads();
        #pragma unroll
        for (int kk = 0; kk < 64; kk += 4) {
            float w0 = W[(size_t)(kb + kk + 0) * ldW + col];
            float w1 = W[(size_t)(kb + kk + 1) * ldW + col];
            float w2 = W[(size_t)(kb + kk + 2) * ldW + col];
            float w3 = W[(size_t)(kb + kk + 3) * ldW + col];
            #pragma unroll
            for (int j = 0; j < 8; ++j) {
                int m = ty + (j << 3);
                float4 xv = *(const float4*)&xs[m][kk];
                acc[j] = fmaf(xv.x, w0, acc[j]);
                acc[j] = fmaf(xv.y, w1, acc[j]);
                acc[j] = fmaf(xv.z, w2, acc[j]);
                acc[j] = fmaf(xv.w, w3, acc[j]);
            }
        }
        __syncthreads();
    }
    if (kc == 0) {
        float b = bias[col];
        #pragma unroll
        for (int j = 0; j < 8; ++j) acc[j] += b;
    }
    const int ldO = (ldW == 2048) ? 2048 : 128;
    #pragma unroll
    for (int j = 0; j < 8; ++j)
        atomicAdd(&out[(size_t)(ty + (j << 3)) * ldO + col], acc[j]);
}

// ---------------------------------------------------------------------------
// K2: flash-decode attention partials (split-KV).
// grid (8 chunks, 64 batches), block 256 (4 waves). Wave w owns 128 slots.
// Per (b,h): 32 partials (m, l, o[128]) written unnormalized.
// ---------------------------------------------------------------------------
__launch_bounds__(256)
__global__ void k2_attn(const float* __restrict__ qbuf,
                        const float* __restrict__ kcache,
                        const float* __restrict__ vcache,
                        const float* __restrict__ knew,
                        const float* __restrict__ vnew,
                        const int* __restrict__ cpos,
                        float* __restrict__ part_o,   // [B][32][16][128]
                        float* __restrict__ part_ml)  // [B][32][16][2]
{
    const int b = blockIdx.y;
    const int chunk = blockIdx.x;
    const int tid = threadIdx.x;
    const int w = tid >> 6;
    const int lane = tid & 63;
    const int quad = lane >> 4;
    const int lm = lane & 15;
    const int pos = cpos[b];

    // LDS (46.25 KB total -> 3 blocks/CU)
    __shared__ __align__(16) short qs[16 * 136];       // q bf16 [16][136]
    __shared__ __align__(16) short ksh[4][16 * 136];   // per-wave k tile [16][136]
    __shared__ __align__(16) short vsh[4][64 * 40];    // per-wave vT half [64 d][40]
    __shared__ __align__(16) short psh[4][16 * 40];    // per-wave P [16][40]

    // ---- stage q (scaled) as bf16 [16 heads][128 d]
    {
        const int h = tid >> 4, d0 = (tid & 15) << 3;
        const float* src = qbuf + (size_t)b * EMBED + h * HD + d0;
        float4 a = *(const float4*)src;
        float4 c = *(const float4*)(src + 4);
        const float s = 0.08838834764831845f;  // 1/sqrt(128)
        short8v pk;
        pk[0] = f2bf(a.x * s); pk[1] = f2bf(a.y * s);
        pk[2] = f2bf(a.z * s); pk[3] = f2bf(a.w * s);
        pk[4] = f2bf(c.x * s); pk[5] = f2bf(c.y * s);
        pk[6] = f2bf(c.z * s); pk[7] = f2bf(c.w * s);
        *(short8v*)&qs[h * 136 + d0] = pk;
    }
    __syncthreads();

    // q A-fragments in registers: A[m=lane&15][k=quad*8+j], K-steps t*32
    short8v aq[4];
    #pragma unroll
    for (int t = 0; t < 4; ++t)
        aq[t] = *(short8v*)&qs[lm * 136 + t * 32 + quad * 8];

    short* kt = ksh[w];
    short* vt = vsh[w];
    short* pt = psh[w];

    float m_run[4] = {-INFINITY, -INFINITY, -INFINITY, -INFINITY};
    float l_run[4] = {0, 0, 0, 0};
    floatx4 oacc[8];
    #pragma unroll
    for (int i = 0; i < 8; ++i) oacc[i] = (floatx4){0, 0, 0, 0};

    const int sbase = chunk * 512 + w * 128;

    for (int st = 0; st < 4; ++st) {
        const int st0 = sbase + st * 32;
        floatx4 sc2[2];
        // ---- QK for two 16-slot tiles
        #pragma unroll
        for (int half = 0; half < 2; ++half) {
            const int s0 = st0 + half * 16;
            float4 tmp[8];
            #pragma unroll
            for (int i = 0; i < 8; ++i) {
                int f = i * 64 + lane;
                tmp[i] = *(const float4*)(kcache +
                    ((size_t)b * S_TOT + s0 + (f >> 5)) * HD + (f & 31) * 4);
            }
            #pragma unroll
            for (int i = 0; i < 8; ++i) {
                int f = i * 64 + lane;
                short4v pk;
                pk[0] = f2bf(tmp[i].x); pk[1] = f2bf(tmp[i].y);
                pk[2] = f2bf(tmp[i].z); pk[3] = f2bf(tmp[i].w);
                *(short4v*)&kt[(f >> 5) * 136 + (f & 31) * 4] = pk;
            }
            // substitute k_new at cache position (wave-uniform branch)
            const int pr = pos - s0;
            if (pr >= 0 && pr < 16) {
                float2 kv = *(const float2*)(knew + b * HD + lane * 2);
                short2v p2; p2[0] = f2bf(kv.x); p2[1] = f2bf(kv.y);
                *(short2v*)&kt[pr * 136 + lane * 2] = p2;
            }
            floatx4 s = {0, 0, 0, 0};
            #pragma unroll
            for (int t = 0; t < 4; ++t) {
                short8v bk_ = *(short8v*)&kt[lm * 136 + t * 32 + quad * 8];
                s = __builtin_amdgcn_mfma_f32_16x16x32_bf16(aq[t], bk_, s, 0, 0, 0);
            }
            sc2[half] = s;
        }
        // ---- online softmax over the 32 slots (rows = heads, via DPP reduce)
        float alpha[4];
        #pragma unroll
        for (int r = 0; r < 4; ++r) {
            float mt = rowmax16(fmaxf(sc2[0][r], sc2[1][r]));
            float mn = fmaxf(m_run[r], mt);
            alpha[r] = __expf(m_run[r] - mn);
            m_run[r] = mn;
            float pA = __expf(sc2[0][r] - mn);
            float pB = __expf(sc2[1][r] - mn);
            float ss = rowsum16(pA + pB);
            l_run[r] = l_run[r] * alpha[r] + ss;
            pt[(quad * 4 + r) * 40 + lm]      = (short)f2bf(pA);
            pt[(quad * 4 + r) * 40 + 16 + lm] = (short)f2bf(pB);
        }
        #pragma unroll
        for (int dt = 0; dt < 8; ++dt) {
            oacc[dt][0] *= alpha[0]; oacc[dt][1] *= alpha[1];
            oacc[dt][2] *= alpha[2]; oacc[dt][3] *= alpha[3];
        }
        // P A-fragment: A[m=h=lane&15][k=slot=quad*8+j]
        short8v ap = *(short8v*)&pt[lm * 40 + quad * 8];

        // ---- PV in two d-halves (vT staged transposed: vt[d_local][slot])
        #pragma unroll
        for (int p = 0; p < 2; ++p) {
            const int sg = lane & 7;     // slot group (4 slots)
            const int dgv = lane >> 3;   // 8 d-groups
            #pragma unroll
            for (int i = 0; i < 2; ++i) {
                int dl = dgv * 4 + i * 32;        // local d 0..60
                int dglob = p * 64 + dl;
                const float* vb = vcache + ((size_t)b * S_TOT + st0 + sg * 4) * HD + dglob;
                float4 r0 = *(const float4*)(vb + 0 * HD);
                float4 r1 = *(const float4*)(vb + 1 * HD);
                float4 r2 = *(const float4*)(vb + 2 * HD);
                float4 r3 = *(const float4*)(vb + 3 * HD);
                short4v p0, p1, p2, p3;
                p0[0]=f2bf(r0.x); p0[1]=f2bf(r1.x); p0[2]=f2bf(r2.x); p0[3]=f2bf(r3.x);
                p1[0]=f2bf(r0.y); p1[1]=f2bf(r1.y); p1[2]=f2bf(r2.y); p1[3]=f2bf(r3.y);
                p2[0]=f2bf(r0.z); p2[1]=f2bf(r1.z); p2[2]=f2bf(r2.z); p2[3]=f2bf(r3.z);
                p3[0]=f2bf(r0.w); p3[1]=f2bf(r1.w); p3[2]=f2bf(r2.w); p3[3]=f2bf(r3.w);
                *(short4v*)&vt[(dl + 0) * 40 + sg * 4] = p0;
                *(short4v*)&vt[(dl + 1) * 40 + sg * 4] = p1;
                *(short4v*)&vt[(dl + 2) * 40 + sg * 4] = p2;
                *(short4v*)&vt[(dl + 3) * 40 + sg * 4] = p3;
            }
            // substitute v_new column (wave-uniform branch)
            const int prs = pos - st0;
            if (prs >= 0 && prs < 32) {
                float vvn = vnew[b * HD + p * 64 + lane];
                vt[lane * 40 + prs] = (short)f2bf(vvn);
            }
            #pragma unroll
            for (int dq = 0; dq < 4; ++dq) {
                int dt = p * 4 + dq;
                short8v bv_ = *(short8v*)&vt[(dq * 16 + lm) * 40 + quad * 8];
                oacc[dt] = __builtin_amdgcn_mfma_f32_16x16x32_bf16(ap, bv_, oacc[dt], 0, 0, 0);
            }
        }
    }

    // ---- write per-wave partials
    const int cw = chunk * 4 + w;
    float* po = part_o + (size_t)(b * 32 + cw) * 16 * 128;
    #pragma unroll
    for (int dt = 0; dt < 8; ++dt)
        #pragma unroll
        for (int r = 0; r < 4; ++r)
            po[(quad * 4 + r) * 128 + dt * 16 + lm] = oacc[dt][r];
    if (lm < 2) {
        #pragma unroll
        for (int r = 0; r < 4; ++r) {
            float v = (lm == 0) ? m_run[r] : l_run[r];
            part_ml[((size_t)(b * 32 + cw) * 16 + quad * 4 + r) * 2 + lm] = v;
        }
    }
}

// ---------------------------------------------------------------------------
// K3: combine 32 partials per (b,h) -> attn[b][h*128+d]
// grid (16 heads, 64 batches), block 128 (thread = d)
// ---------------------------------------------------------------------------
__launch_bounds__(128)
__global__ void k3_combine(const float* __restrict__ part_o,
                           const float* __restrict__ part_ml,
                           float* __restrict__ attn) {
    const int h = blockIdx.x, b = blockIdx.y, d = threadIdx.x;
    __shared__ float sm[32], sl[32];
    if (threadIdx.x < 32) {
        sm[threadIdx.x] = part_ml[((size_t)(b * 32 + threadIdx.x) * 16 + h) * 2 + 0];
        sl[threadIdx.x] = part_ml[((size_t)(b * 32 + threadIdx.x) * 16 + h) * 2 + 1];
    }
    __syncthreads();
    float M = -INFINITY;
    #pragma unroll
    for (int c = 0; c < 32; ++c) M = fmaxf(M, sm[c]);
    float O = 0.f, L = 0.f;
    for (int c = 0; c < 32; ++c) {
        float co = __expf(sm[c] - M);
        L += co * sl[c];
        O += co * part_o[((size_t)(b * 32 + c) * 16 + h) * 128 + d];
    }
    attn[(size_t)b * EMBED + h * HD + d] = O / L;
}

// ---------------------------------------------------------------------------
// K4: output projection. out = attn @ Wo + bo, M=64, N=2048, K=2048
// grid (64 n-tiles, 8 k-splits), block 256. Atomic into memset d_out.
// ---------------------------------------------------------------------------
__launch_bounds__(256)
__global__ void k4_proj(const float* __restrict__ attn,
                        const float* __restrict__ Wo, const float* __restrict__ bo,
                        float* __restrict__ out) {
    const int tx = threadIdx.x & 31;
    const int ty = threadIdx.x >> 5;
    const int col = blockIdx.x * 32 + tx;
    const int k0 = blockIdx.y * 256;

    __shared__ __align__(16) float xs[64][68];
    float acc[8] = {0, 0, 0, 0, 0, 0, 0, 0};

    for (int sub = 0; sub < 4; ++sub) {
        const int kb = k0 + sub * 64;
        #pragma unroll
        for (int i = 0; i < 4; ++i) {
            int c = threadIdx.x + i * 256;
            int r = c >> 4;
            int cc = (c & 15) << 2;
            float4 v = *(const float4*)(attn + (size_t)r * EMBED + kb + cc);
            *(float4*)&xs[r][cc] = v;
        }
        __syncthreads();
        #pragma unroll
        for (int kk = 0; kk < 64; kk += 4) {
            float w0 = Wo[(size_t)(kb + kk + 0) * EMBED + col];
            float w1 = Wo[(size_t)(kb + kk + 1) * EMBED + col];
            float w2 = Wo[(size_t)(kb + kk + 2) * EMBED + col];
            float w3 = Wo[(size_t)(kb + kk + 3) * EMBED + col];
            #pragma unroll
            for (int j = 0; j < 8; ++j) {
                int m = ty + (j << 3);
                float4 xv = *(const float4*)&xs[m][kk];
                acc[j] = fmaf(xv.x, w0, acc[j]);
                acc[j] = fmaf(xv.y, w1, acc[j]);
                acc[j] = fmaf(xv.z, w2, acc[j]);
                acc[j] = fmaf(xv.w, w3, acc[j]);
            }
        }
        __syncthreads();
    }
    if (blockIdx.y == 0) {
        float b = bo[col];
        #pragma unroll
        for (int j = 0; j < 8; ++j) acc[j] += b;
    }
    #pragma unroll
    for (int j = 0; j < 8; ++j)
        atomicAdd(&out[(size_t)(ty + (j << 3)) * EMBED + col], acc[j]);
}

// ---------------------------------------------------------------------------
extern "C" void kernel_launch(void* const* d_in, const int* in_sizes, int n_in,
                              void* d_out, int out_size, void* d_ws, size_t ws_size,
                              hipStream_t stream) {
    (void)in_sizes; (void)n_in; (void)out_size; (void)ws_size;
    const float* x  = (const float*)d_in[0];
    const float* kc = (const float*)d_in[1];
    const float* vc = (const float*)d_in[2];
    const int*   cp = (const int*)d_in[3];
    const float* Wq = (const float*)d_in[4];
    const float* bq = (const float*)d_in[5];
    const float* Wk = (const float*)d_in[6];
    const float* bk = (const float*)d_in[7];
    const float* Wv = (const float*)d_in[8];
    const float* bv = (const float*)d_in[9];
    const float* Wo = (const float*)d_in[10];
    const float* bo = (const float*)d_in[11];
    float* out = (float*)d_out;
    float* ws  = (float*)d_ws;

    // ws layout (floats)
    float* qbuf = ws;                    // 131072
    float* knew = ws + 131072;           // 8192
    float* vnew = ws + 139264;           // 8192
    float* attn = ws + 147456;           // 131072
    float* po   = ws + 278528;           // 64*32*16*128 = 4194304
    float* pml  = ws + 4472832;          // 64*32*16*2   = 65536
    // total 4538368 floats = 18.2 MB

    hipMemsetAsync(qbuf, 0, 147456 * sizeof(float), stream);   // q/k_new/v_new
    hipMemsetAsync(out, 0, (size_t)BATCH * EMBED * sizeof(float), stream);

    k1_qkv<<<dim3(72, 8), 256, 0, stream>>>(x, Wq, bq, Wk, bk, Wv, bv, qbuf, knew, vnew);
    k2_attn<<<dim3(8, 64), 256, 0, stream>>>(qbuf, kc, vc, knew, vnew, cp, po, pml);
    k3_combine<<<dim3(16, 64), 128, 0, stream>>>(po, pml, attn);
    k4_proj<<<dim3(64, 8), 256, 0, stream>>>(attn, Wo, bo, out);
}